// Round 2
// baseline (1078.660 us; speedup 1.0000x reference)
//
#include <hip/hip_runtime.h>

#define D 64
#define HOUR_PERIOD 6

// ---------- dtype helpers ----------
__device__ __forceinline__ float bf2f(unsigned short u) {
    union { unsigned int i; float f; } v; v.i = ((unsigned int)u) << 16; return v.f;
}
__device__ __forceinline__ unsigned short f2bf(float f) {
    union { float fl; unsigned int i; } v; v.fl = f;
    unsigned int x = v.i;
    return (unsigned short)((x + 0x7fffu + ((x >> 16) & 1u)) >> 16);
}
// load 4 consecutive elements (element offset = idx4*4) as float4, dual dtype
__device__ __forceinline__ float4 ld4(const void* base, int idx4, int fp32) {
    if (fp32) return reinterpret_cast<const float4*>(base)[idx4];
    ushort4 u = reinterpret_cast<const ushort4*>(base)[idx4];
    return make_float4(bf2f(u.x), bf2f(u.y), bf2f(u.z), bf2f(u.w));
}
__device__ __forceinline__ float ld1(const void* base, int i, int fp32) {
    return fp32 ? reinterpret_cast<const float*>(base)[i]
                : bf2f(reinterpret_cast<const unsigned short*>(base)[i]);
}

// ---------- dtype detection ----------
// rel_emb rows are L2-normalized: every true element |v| <= 1.
// If the buffer is really fp32 and we read it as bf16, even-index elements are
// the float's low mantissa bits -> ~47% chance |v| > 128 each; 128 samples make
// a false negative impossible in practice. NaN compares false -> counted bad.
__global__ void k_detect(const unsigned short* __restrict__ rel, int* __restrict__ flag) {
    int t = threadIdx.x;
    float a = bf2f(rel[t]);
    float b = bf2f(rel[t + 64]);
    int bad = (!(fabsf(a) <= 100.f)) || (!(fabsf(b) <= 100.f));
    unsigned long long m = __ballot(bad);
    if (t == 0) *flag = (m != 0ull) ? 1 : 0;   // 1 => fp32 inputs/outputs
}

// ---------- zero a float region ----------
__global__ void k_zero(float* __restrict__ p, int n) {
    int i = blockIdx.x * blockDim.x + threadIdx.x;
    int i4 = i * 4;
    if (i4 + 3 < n) {
        reinterpret_cast<float4*>(p)[i] = make_float4(0.f, 0.f, 0.f, 0.f);
    } else {
        for (int k = i4; k < n; ++k) p[k] = 0.f;
    }
}

// ---------- precompute time_rel table (6 distinct hour mixes) ----------
__global__ void k_trel(const void* __restrict__ hour_emb, const void* __restrict__ W,
                       const void* __restrict__ b, const int* __restrict__ flag,
                       float* __restrict__ trel) {
    int f = *flag;
    int hid = blockIdx.x;      // 0..5
    int j = threadIdx.x;       // 0..63
    __shared__ float mix[D];
    int last = (hid - 1 + HOUR_PERIOD) % HOUR_PERIOD;
    int next = (hid + 1) % HOUR_PERIOD;
    mix[j] = (ld1(hour_emb, last * D + j, f) + ld1(hour_emb, hid * D + j, f) +
              ld1(hour_emb, next * D + j, f)) * (1.f / 3.f);
    __syncthreads();
    float y = ld1(b, j, f);
    #pragma unroll
    for (int k = 0; k < D; ++k) y += mix[k] * ld1(W, j * D + k, f);
    float ss = y * y;
    #pragma unroll
    for (int off = 32; off; off >>= 1) ss += __shfl_xor(ss, off, 64);
    trel[hid * D + j] = y / fmaxf(sqrtf(ss), 1e-12f);
}

// ---------- main graph pass 1: TransH scores + exp-sum per dst ----------
// 16 threads/edge, 4 dims/thread.
__global__ void k_main_p1(const void* __restrict__ nfeat, const void* __restrict__ rel_emb,
                          const void* __restrict__ norm_emb, const float* __restrict__ trel,
                          const int* __restrict__ src, const int* __restrict__ dst,
                          const int* __restrict__ ftype, const int* __restrict__ hourid,
                          const int* __restrict__ flag,
                          float* __restrict__ fin, float* __restrict__ sum, int E) {
    int f = *flag;
    int t = blockIdx.x * blockDim.x + threadIdx.x;
    int e = t >> 4;
    int l = threadIdx.x & 15;
    if (e >= E) return;
    int s = src[e], d = dst[e], ft = ftype[e], hh = hourid[e];
    float4 h = ld4(nfeat, s * 16 + l, f);
    float4 tt = ld4(nfeat, d * 16 + l, f);
    float4 nn = ld4(norm_emb, ft * 16 + l, f);
    float4 qq = ld4(norm_emb, 5 * 16 + l, f);
    float w0 = h.x - tt.x, w1 = h.y - tt.y, w2 = h.z - tt.z, w3 = h.w - tt.w;
    float alpha = w0 * nn.x + w1 * nn.y + w2 * nn.z + w3 * nn.w;   // (h-t)·norm
    float beta  = w0 * qq.x + w1 * qq.y + w2 * qq.z + w3 * qq.w;   // (h-t)·time_norm
    #pragma unroll
    for (int off = 8; off; off >>= 1) {
        alpha += __shfl_xor(alpha, off, 16);
        beta  += __shfl_xor(beta,  off, 16);
    }
    float4 rr = ld4(rel_emb, ft * 16 + l, f);
    float4 tr = reinterpret_cast<const float4*>(trel)[hh * 16 + l];
    float u0 = w0 + rr.x - alpha * nn.x, u1 = w1 + rr.y - alpha * nn.y,
          u2 = w2 + rr.z - alpha * nn.z, u3 = w3 + rr.w - alpha * nn.w;
    float v0 = w0 + tr.x - beta * qq.x, v1 = w1 + tr.y - beta * qq.y,
          v2 = w2 + tr.z - beta * qq.z, v3 = w3 + tr.w - beta * qq.w;
    float ssq = u0*u0 + u1*u1 + u2*u2 + u3*u3 + v0*v0 + v1*v1 + v2*v2 + v3*v3;
    #pragma unroll
    for (int off = 8; off; off >>= 1) ssq += __shfl_xor(ssq, off, 16);
    if (l == 0) {
        // fin_score = exp(-ssq) in (0,1]; softmax numerator exp(fin_score) in (1,e]
        // -> max-subtraction is unnecessary for stability.
        float es = __expf(__expf(-ssq));
        fin[e] = es;
        atomicAdd(&sum[d], es);
    }
}

// ---------- category graph pass 1: TransE score + exp-sum ----------
__global__ void k_cat_p1(const void* __restrict__ cemb, const void* __restrict__ rel_emb,
                         const int* __restrict__ csrc, const int* __restrict__ cdst,
                         const int* __restrict__ flag,
                         float* __restrict__ cfin, float* __restrict__ csum, int EC) {
    int f = *flag;
    int t = blockIdx.x * blockDim.x + threadIdx.x;
    int e = t >> 4;
    int l = threadIdx.x & 15;
    if (e >= EC) return;
    int s = csrc[e], d = cdst[e];
    float4 h = ld4(cemb, s * 16 + l, f);
    float4 tt = ld4(cemb, d * 16 + l, f);
    float4 rr = ld4(rel_emb, 6 * 16 + l, f);
    float d0 = h.x + rr.x - tt.x, d1 = h.y + rr.y - tt.y,
          d2 = h.z + rr.z - tt.z, d3 = h.w + rr.w - tt.w;
    float ssq = d0*d0 + d1*d1 + d2*d2 + d3*d3;
    #pragma unroll
    for (int off = 8; off; off >>= 1) ssq += __shfl_xor(ssq, off, 16);
    if (l == 0) {
        float es = __expf(__expf(-ssq));
        cfin[e] = es;
        atomicAdd(&csum[d], es);
    }
}

// ---------- pass 2: a = num/sum[dst]; acc[dst-lo] += h*a (dst in [lo,hi)) ----------
__global__ void k_p2(const void* __restrict__ feat,
                     const int* __restrict__ src, const int* __restrict__ dst,
                     const float* __restrict__ fin, const float* __restrict__ sum,
                     const int* __restrict__ flag,
                     float* __restrict__ acc, int E, int lo, int hi) {
    int f = *flag;
    int t = blockIdx.x * blockDim.x + threadIdx.x;
    int e = t >> 4;
    int l = threadIdx.x & 15;
    if (e >= E) return;
    int d = dst[e];
    if (d < lo || d >= hi) return;
    int s = src[e];
    float a = fin[e] / sum[d];
    float4 h = ld4(feat, s * 16 + l, f);
    float* o = acc + (d - lo) * D + l * 4;
    atomicAdd(o + 0, h.x * a);
    atomicAdd(o + 1, h.y * a);
    atomicAdd(o + 2, h.z * a);
    atomicAdd(o + 3, h.w * a);
}

// ---------- finalize: f32 accumulator chunk -> output rows [rowBase, rowBase+rows) ----------
__global__ void k_final(const float4* __restrict__ acc, void* __restrict__ out,
                        const int* __restrict__ flag, int rowBase, int rows) {
    int f = *flag;
    int i = blockIdx.x * blockDim.x + threadIdx.x;
    int n4 = rows * (D / 4);
    if (i >= n4) return;
    float4 v = acc[i];
    int oi = rowBase * (D / 4) + i;
    if (f) {
        reinterpret_cast<float4*>(out)[oi] = v;
    } else {
        ushort4 o;
        o.x = f2bf(v.x); o.y = f2bf(v.y); o.z = f2bf(v.z); o.w = f2bf(v.w);
        reinterpret_cast<ushort4*>(out)[oi] = o;
    }
}

extern "C" void kernel_launch(void* const* d_in, const int* in_sizes, int n_in,
                              void* d_out, int out_size, void* d_ws, size_t ws_size,
                              hipStream_t stream) {
    const void* nfeat    = d_in[0];
    const void* cemb     = d_in[1];
    const void* rel_emb  = d_in[2];
    const void* norm_emb = d_in[3];
    const void* hour_emb = d_in[4];
    const void* trw      = d_in[5];
    const void* trb      = d_in[6];
    const int* src    = (const int*)d_in[7];
    const int* dst    = (const int*)d_in[8];
    const int* ftype  = (const int*)d_in[9];
    const int* hourid = (const int*)d_in[10];
    const int* csrc   = (const int*)d_in[11];
    const int* cdst   = (const int*)d_in[12];

    const int N  = in_sizes[0] / D;
    const int NC = in_sizes[1] / D;
    const int E  = in_sizes[7];
    const int EC = in_sizes[11];

    // ---- ws layout (floats), fixed part first so racc can size to what's left ----
    float* ws = (float*)d_ws;
    int*   flag = (int*)ws;                         // [0..15] flag + pad (keeps alignment)
    float* trel = ws + 16;                          // 6*D
    float* sum  = trel + HOUR_PERIOD * D;           // N
    float* csum = sum + N;                          // NC
    float* cacc = csum + NC;                        // NC*D
    float* fin  = cacc + (long)NC * D;              // E
    float* cfin = fin + E;                          // EC
    float* racc = cfin + EC;                        // up to N*D, chunked to fit ws
    long fixedEnd = 16 + (long)HOUR_PERIOD * D + N + NC + (long)NC * D + E + EC;

    long wsF = (long)(ws_size / 4);
    long avail = wsF - fixedEnd;
    long chunkRows = avail / D;
    if (chunkRows > N) chunkRows = N;
    long minRows = (N + 63) / 64;                   // cap at 64 chunks
    if (chunkRows < minRows) chunkRows = minRows;   // (if ws is truly tiny nothing saves us)
    int K = (int)((N + chunkRows - 1) / chunkRows);

    k_detect<<<1, 64, 0, stream>>>((const unsigned short*)rel_emb, flag);

    // zero sum + csum + cacc (contiguous)
    {
        int zn = N + NC + NC * D;
        k_zero<<<((zn + 3) / 4 + 255) / 256, 256, 0, stream>>>(sum, zn);
    }

    k_trel<<<HOUR_PERIOD, D, 0, stream>>>(hour_emb, trw, trb, flag, trel);

    long mainThreads = (long)E * 16;
    long catThreads  = (long)EC * 16;
    int mainBlocks = (int)((mainThreads + 255) / 256);
    int catBlocks  = (int)((catThreads + 255) / 256);

    k_cat_p1<<<catBlocks, 256, 0, stream>>>(cemb, rel_emb, csrc, cdst, flag, cfin, csum, EC);
    k_main_p1<<<mainBlocks, 256, 0, stream>>>(nfeat, rel_emb, norm_emb, trel,
                                              src, dst, ftype, hourid, flag, fin, sum, E);

    // category pass 2 (cacc is in the fixed region, no chunking)
    k_p2<<<catBlocks, 256, 0, stream>>>(cemb, csrc, cdst, cfin, csum, flag, cacc, EC, 0, NC);

    // main pass 2, chunked over dst ranges to fit racc in remaining ws
    for (int c = 0; c < K; ++c) {
        int lo = (int)((long)c * chunkRows);
        int rows = (int)((lo + chunkRows <= N) ? chunkRows : (N - lo));
        int zn = rows * D;
        k_zero<<<((zn + 3) / 4 + 255) / 256, 256, 0, stream>>>(racc, zn);
        k_p2<<<mainBlocks, 256, 0, stream>>>(nfeat, src, dst, fin, sum, flag,
                                             racc, E, lo, lo + rows);
        int fb = (rows * (D / 4) + 255) / 256;
        k_final<<<fb, 256, 0, stream>>>((const float4*)racc, d_out, flag, lo, rows);
    }

    // category output rows start at row N of the concatenated output
    {
        int fb = (NC * (D / 4) + 255) / 256;
        k_final<<<fb, 256, 0, stream>>>((const float4*)cacc, d_out, flag, N, NC);
    }
}

// Round 3
// 299.421 us; speedup vs baseline: 3.6025x; 3.6025x over previous
//
#include <hip/hip_runtime.h>

#define D 64
#define HOUR_PERIOD 6

// ---------- dtype helpers ----------
__device__ __forceinline__ float bf2f(unsigned short u) {
    union { unsigned int i; float f; } v; v.i = ((unsigned int)u) << 16; return v.f;
}
__device__ __forceinline__ unsigned short f2bf(float f) {
    union { float fl; unsigned int i; } v; v.fl = f;
    unsigned int x = v.i;
    return (unsigned short)((x + 0x7fffu + ((x >> 16) & 1u)) >> 16);
}
// load 4 consecutive elements (element offset = idx4*4) as float4, dual dtype
__device__ __forceinline__ float4 ld4(const void* base, int idx4, int fp32) {
    if (fp32) return reinterpret_cast<const float4*>(base)[idx4];
    ushort4 u = reinterpret_cast<const ushort4*>(base)[idx4];
    return make_float4(bf2f(u.x), bf2f(u.y), bf2f(u.z), bf2f(u.w));
}
__device__ __forceinline__ float ld1(const void* base, int i, int fp32) {
    return fp32 ? reinterpret_cast<const float*>(base)[i]
                : bf2f(reinterpret_cast<const unsigned short*>(base)[i]);
}
// quarter-wave (16-lane) butterfly sum
__device__ __forceinline__ float qsum(float v) {
    v += __shfl_xor(v, 8, 16);
    v += __shfl_xor(v, 4, 16);
    v += __shfl_xor(v, 2, 16);
    v += __shfl_xor(v, 1, 16);
    return v;
}

// ---------- dtype detection (rel_emb rows are L2-normalized: |v|<=1 if bf16) ----------
__global__ void k_detect(const unsigned short* __restrict__ rel, int* __restrict__ flag) {
    int t = threadIdx.x;
    float a = bf2f(rel[t]);
    float b = bf2f(rel[t + 64]);
    int bad = (!(fabsf(a) <= 100.f)) || (!(fabsf(b) <= 100.f));
    unsigned long long m = __ballot(bad);
    if (t == 0) *flag = (m != 0ull) ? 1 : 0;   // 1 => fp32 inputs/outputs
}

// ---------- zero int/float region ----------
__global__ void k_zero(int* __restrict__ p, int n) {
    int i = blockIdx.x * blockDim.x + threadIdx.x;
    int i4 = i * 4;
    if (i4 + 3 < n) {
        reinterpret_cast<int4*>(p)[i] = make_int4(0, 0, 0, 0);
    } else {
        for (int k = i4; k < n; ++k) p[k] = 0;
    }
}

// ---------- precompute time_rel table (6 distinct hour mixes) ----------
__global__ void k_trel(const void* __restrict__ hour_emb, const void* __restrict__ W,
                       const void* __restrict__ b, const int* __restrict__ flag,
                       float* __restrict__ trel) {
    int f = *flag;
    int hid = blockIdx.x;      // 0..5
    int j = threadIdx.x;       // 0..63
    __shared__ float mix[D];
    int last = (hid - 1 + HOUR_PERIOD) % HOUR_PERIOD;
    int next = (hid + 1) % HOUR_PERIOD;
    mix[j] = (ld1(hour_emb, last * D + j, f) + ld1(hour_emb, hid * D + j, f) +
              ld1(hour_emb, next * D + j, f)) * (1.f / 3.f);
    __syncthreads();
    float y = ld1(b, j, f);
    #pragma unroll
    for (int k = 0; k < D; ++k) y += mix[k] * ld1(W, j * D + k, f);
    float ss = y * y;
    #pragma unroll
    for (int off = 32; off; off >>= 1) ss += __shfl_xor(ss, off, 64);
    trel[hid * D + j] = y / fmaxf(sqrtf(ss), 1e-12f);
}

// ---------- CSR build: histogram ----------
__global__ void k_hist(const int* __restrict__ dst, int* __restrict__ cnt, int n) {
    int i = blockIdx.x * blockDim.x + threadIdx.x;
    if (i < n) atomicAdd(&cnt[dst[i]], 1);
}

// ---------- CSR build: hierarchical exclusive scan (chunk = 1024 per block) ----------
__global__ void k_scanA(const int* __restrict__ cnt, int* __restrict__ parts, int n) {
    __shared__ int sm[256];
    int t = threadIdx.x, b = blockIdx.x;
    int base = b * 1024 + t * 4;
    int s = 0;
    #pragma unroll
    for (int k = 0; k < 4; ++k) { int i = base + k; if (i < n) s += cnt[i]; }
    sm[t] = s; __syncthreads();
    #pragma unroll
    for (int off = 128; off; off >>= 1) {
        if (t < off) sm[t] += sm[t + off];
        __syncthreads();
    }
    if (t == 0) parts[b] = sm[0];
}
__global__ void k_scanB(int* __restrict__ parts, int nparts) {
    __shared__ int sm[256];
    int t = threadIdx.x;
    int v = (t < nparts) ? parts[t] : 0;
    sm[t] = v; __syncthreads();
    for (int off = 1; off < 256; off <<= 1) {
        int x = (t >= off) ? sm[t - off] : 0;
        __syncthreads();
        sm[t] += x;
        __syncthreads();
    }
    if (t < nparts) parts[t] = sm[t] - v;   // exclusive base per chunk
}
__global__ void k_scanC(const int* __restrict__ cnt, const int* __restrict__ parts,
                        int* __restrict__ row, int* __restrict__ cur, int n) {
    __shared__ int sm[256];
    int t = threadIdx.x, b = blockIdx.x;
    int base = b * 1024 + t * 4;
    int c[4]; int s = 0;
    #pragma unroll
    for (int k = 0; k < 4; ++k) { int i = base + k; c[k] = (i < n) ? cnt[i] : 0; s += c[k]; }
    sm[t] = s; __syncthreads();
    int inc = s;
    for (int off = 1; off < 256; off <<= 1) {
        int x = (t >= off) ? sm[t - off] : 0;
        __syncthreads();
        sm[t] += x;
        __syncthreads();
    }
    inc = sm[t];
    int run = parts[b] + (inc - s);   // exclusive across threads
    #pragma unroll
    for (int k = 0; k < 4; ++k) {
        int i = base + k;
        if (i < n) {
            row[i] = run; cur[i] = run;
            if (i == n - 1) row[n] = run + c[k];
            run += c[k];
        }
    }
}

// ---------- CSR build: scatter packed edge records ----------
// pack: src (17b) | ftype (3b) | hour (3b). For cat graph ft/hh are null -> src only.
__global__ void k_scatter(const int* __restrict__ src, const int* __restrict__ dst,
                          const int* __restrict__ ft, const int* __restrict__ hh,
                          int* __restrict__ cur, unsigned* __restrict__ recs, int n) {
    int i = blockIdx.x * blockDim.x + threadIdx.x;
    if (i >= n) return;
    int d = dst[i];
    int p = atomicAdd(&cur[d], 1);
    unsigned pk = (unsigned)src[i];
    if (ft) pk |= ((unsigned)ft[i] << 17) | ((unsigned)hh[i] << 20);
    recs[p] = pk;
}

// ---------- fused main: per-dst quarter-wave, scores + weighted average ----------
// rst[d] = sum_e es_e * h_e / sum_e es_e   (softmax denominator factors out)
__launch_bounds__(256)
__global__ void k_fused_main(const void* __restrict__ nfeat, const void* __restrict__ rel_emb,
                             const void* __restrict__ norm_emb, const float* __restrict__ trel,
                             const int* __restrict__ row, const unsigned* __restrict__ recs,
                             const int* __restrict__ flag, void* __restrict__ out, int nNodes) {
    int f = *flag;
    __shared__ float srel[7 * D], snorm[7 * D], strel[HOUR_PERIOD * D];
    int tid = threadIdx.x;
    for (int i = tid; i < 7 * D; i += 256) srel[i] = ld1(rel_emb, i, f);
    for (int i = tid; i < 7 * D; i += 256) snorm[i] = ld1(norm_emb, i, f);
    for (int i = tid; i < HOUR_PERIOD * D; i += 256) strel[i] = trel[i];
    __syncthreads();
    int l = tid & 15;
    int d = blockIdx.x * 16 + (tid >> 4);
    if (d >= nNodes) return;
    float4 tt = ld4(nfeat, d * 16 + l, f);
    float4 qq = *reinterpret_cast<float4*>(&snorm[5 * D + l * 4]);   // time_norm
    int i0 = row[d], i1 = row[d + 1];
    float a0 = 0.f, a1 = 0.f, a2 = 0.f, a3 = 0.f, se = 0.f;
    unsigned pk = 0; float4 h = make_float4(0, 0, 0, 0);
    if (i0 < i1) { pk = recs[i0]; h = ld4(nfeat, (int)(pk & 0x1FFFF) * 16 + l, f); }
    for (int i = i0; i < i1; ++i) {
        unsigned cpk = pk; float4 ch = h;
        if (i + 1 < i1) { pk = recs[i + 1]; h = ld4(nfeat, (int)(pk & 0x1FFFF) * 16 + l, f); }
        int ft = (cpk >> 17) & 7, hh = (cpk >> 20) & 7;
        float4 nn = *reinterpret_cast<float4*>(&snorm[ft * D + l * 4]);
        float4 rr = *reinterpret_cast<float4*>(&srel[ft * D + l * 4]);
        float4 tr = *reinterpret_cast<float4*>(&strel[hh * D + l * 4]);
        float w0 = ch.x - tt.x, w1 = ch.y - tt.y, w2 = ch.z - tt.z, w3 = ch.w - tt.w;
        float alpha = qsum(w0 * nn.x + w1 * nn.y + w2 * nn.z + w3 * nn.w);
        float beta  = qsum(w0 * qq.x + w1 * qq.y + w2 * qq.z + w3 * qq.w);
        float u0 = w0 + rr.x - alpha * nn.x, u1 = w1 + rr.y - alpha * nn.y,
              u2 = w2 + rr.z - alpha * nn.z, u3 = w3 + rr.w - alpha * nn.w;
        float v0 = w0 + tr.x - beta * qq.x, v1 = w1 + tr.y - beta * qq.y,
              v2 = w2 + tr.z - beta * qq.z, v3 = w3 + tr.w - beta * qq.w;
        float ssq = qsum(u0*u0 + u1*u1 + u2*u2 + u3*u3 +
                         v0*v0 + v1*v1 + v2*v2 + v3*v3);
        float es = __expf(__expf(-ssq));   // exp(fin_score), fin_score in (0,1]
        a0 += es * ch.x; a1 += es * ch.y; a2 += es * ch.z; a3 += es * ch.w;
        se += es;
    }
    float inv = (se > 0.f) ? 1.f / se : 0.f;   // zero-degree row -> zeros
    int oi = d * 16 + l;
    if (f) {
        reinterpret_cast<float4*>(out)[oi] = make_float4(a0*inv, a1*inv, a2*inv, a3*inv);
    } else {
        ushort4 o;
        o.x = f2bf(a0*inv); o.y = f2bf(a1*inv); o.z = f2bf(a2*inv); o.w = f2bf(a3*inv);
        reinterpret_cast<ushort4*>(out)[oi] = o;
    }
}

// ---------- fused category graph: TransE score + weighted average ----------
__launch_bounds__(256)
__global__ void k_fused_cat(const void* __restrict__ cemb, const void* __restrict__ rel_emb,
                            const int* __restrict__ row, const unsigned* __restrict__ recs,
                            const int* __restrict__ flag, void* __restrict__ out,
                            int nc, int rowBase) {
    int f = *flag;
    int tid = threadIdx.x;
    int l = tid & 15;
    int d = blockIdx.x * 16 + (tid >> 4);
    if (d >= nc) return;
    float4 tt = ld4(cemb, d * 16 + l, f);
    float4 r6 = ld4(rel_emb, 6 * 16 + l, f);
    float b0 = r6.x - tt.x, b1 = r6.y - tt.y, b2 = r6.z - tt.z, b3 = r6.w - tt.w;
    int i0 = row[d], i1 = row[d + 1];
    float a0 = 0.f, a1 = 0.f, a2 = 0.f, a3 = 0.f, se = 0.f;
    unsigned pk = 0; float4 h = make_float4(0, 0, 0, 0);
    if (i0 < i1) { pk = recs[i0]; h = ld4(cemb, (int)pk * 16 + l, f); }
    for (int i = i0; i < i1; ++i) {
        float4 ch = h;
        if (i + 1 < i1) { pk = recs[i + 1]; h = ld4(cemb, (int)pk * 16 + l, f); }
        float d0 = ch.x + b0, d1 = ch.y + b1, d2 = ch.z + b2, d3 = ch.w + b3;
        float ssq = qsum(d0*d0 + d1*d1 + d2*d2 + d3*d3);
        float es = __expf(__expf(-ssq));
        a0 += es * ch.x; a1 += es * ch.y; a2 += es * ch.z; a3 += es * ch.w;
        se += es;
    }
    float inv = (se > 0.f) ? 1.f / se : 0.f;
    int oi = (rowBase + d) * 16 + l;
    if (f) {
        reinterpret_cast<float4*>(out)[oi] = make_float4(a0*inv, a1*inv, a2*inv, a3*inv);
    } else {
        ushort4 o;
        o.x = f2bf(a0*inv); o.y = f2bf(a1*inv); o.z = f2bf(a2*inv); o.w = f2bf(a3*inv);
        reinterpret_cast<ushort4*>(out)[oi] = o;
    }
}

extern "C" void kernel_launch(void* const* d_in, const int* in_sizes, int n_in,
                              void* d_out, int out_size, void* d_ws, size_t ws_size,
                              hipStream_t stream) {
    const void* nfeat    = d_in[0];
    const void* cemb     = d_in[1];
    const void* rel_emb  = d_in[2];
    const void* norm_emb = d_in[3];
    const void* hour_emb = d_in[4];
    const void* trw      = d_in[5];
    const void* trb      = d_in[6];
    const int* src    = (const int*)d_in[7];
    const int* dst    = (const int*)d_in[8];
    const int* ftype  = (const int*)d_in[9];
    const int* hourid = (const int*)d_in[10];
    const int* csrc   = (const int*)d_in[11];
    const int* cdst   = (const int*)d_in[12];

    const int N  = in_sizes[0] / D;
    const int NC = in_sizes[1] / D;
    const int E  = in_sizes[7];
    const int EC = in_sizes[11];

    // ---- ws layout (4B units), total ~= 3N + 3NC + E + EC + 1426 floats ~= 4.5 MB ----
    int* ws    = (int*)d_ws;
    int* flag  = ws;                         // 16
    float* trel = (float*)(ws + 16);         // HOUR_PERIOD*D = 384
    int* cnt   = ws + 16 + HOUR_PERIOD * D;  // N
    int* ccnt  = cnt + N;                    // NC  (zeroed together with cnt)
    int* row   = ccnt + NC;                  // N+1
    int* crow  = row + N + 1;                // NC+1
    int* cur   = crow + NC + 1;              // N
    int* ccur  = cur + N;                    // NC
    int* parts = ccur + NC;                  // 1024 (scan scratch, reused)
    unsigned* recs  = (unsigned*)(parts + 1024);  // E
    unsigned* crecs = recs + E;                   // EC

    k_detect<<<1, 64, 0, stream>>>((const unsigned short*)rel_emb, flag);
    k_zero<<<((N + NC + 3) / 4 + 255) / 256, 256, 0, stream>>>(cnt, N + NC);
    k_trel<<<HOUR_PERIOD, D, 0, stream>>>(hour_emb, trw, trb, flag, trel);

    // histograms
    k_hist<<<(E + 255) / 256, 256, 0, stream>>>(dst, cnt, E);
    k_hist<<<(EC + 255) / 256, 256, 0, stream>>>(cdst, ccnt, EC);

    // main CSR
    int npartsM = (N + 1023) / 1024;
    k_scanA<<<npartsM, 256, 0, stream>>>(cnt, parts, N);
    k_scanB<<<1, 256, 0, stream>>>(parts, npartsM);
    k_scanC<<<npartsM, 256, 0, stream>>>(cnt, parts, row, cur, N);
    k_scatter<<<(E + 255) / 256, 256, 0, stream>>>(src, dst, ftype, hourid, cur, recs, E);
    k_fused_main<<<(N + 15) / 16, 256, 0, stream>>>(nfeat, rel_emb, norm_emb, trel,
                                                    row, recs, flag, d_out, N);

    // category CSR
    int npartsC = (NC + 1023) / 1024;
    k_scanA<<<npartsC, 256, 0, stream>>>(ccnt, parts, NC);
    k_scanB<<<1, 256, 0, stream>>>(parts, npartsC);
    k_scanC<<<npartsC, 256, 0, stream>>>(ccnt, parts, crow, ccur, NC);
    k_scatter<<<(EC + 255) / 256, 256, 0, stream>>>(csrc, cdst, nullptr, nullptr, ccur, crecs, EC);
    k_fused_cat<<<(NC + 15) / 16, 256, 0, stream>>>(cemb, rel_emb, crow, crecs, flag,
                                                    d_out, NC, N);
}

// Round 4
// 284.585 us; speedup vs baseline: 3.7903x; 1.0521x over previous
//
#include <hip/hip_runtime.h>

#define D 64
#define HOUR_PERIOD 6

// ---------- dtype helpers ----------
__device__ __forceinline__ float bf2f(unsigned short u) {
    union { unsigned int i; float f; } v; v.i = ((unsigned int)u) << 16; return v.f;
}
__device__ __forceinline__ unsigned short f2bf(float f) {
    union { float fl; unsigned int i; } v; v.fl = f;
    unsigned int x = v.i;
    return (unsigned short)((x + 0x7fffu + ((x >> 16) & 1u)) >> 16);
}
__device__ __forceinline__ float4 ld4(const void* base, int idx4, int fp32) {
    if (fp32) return reinterpret_cast<const float4*>(base)[idx4];
    ushort4 u = reinterpret_cast<const ushort4*>(base)[idx4];
    return make_float4(bf2f(u.x), bf2f(u.y), bf2f(u.z), bf2f(u.w));
}
__device__ __forceinline__ float ld1(const void* base, int i, int fp32) {
    return fp32 ? reinterpret_cast<const float*>(base)[i]
                : bf2f(reinterpret_cast<const unsigned short*>(base)[i]);
}
__device__ __forceinline__ float qsum(float v) {   // 16-lane butterfly
    v += __shfl_xor(v, 8, 16);
    v += __shfl_xor(v, 4, 16);
    v += __shfl_xor(v, 2, 16);
    v += __shfl_xor(v, 1, 16);
    return v;
}
__device__ __forceinline__ float wsum64(float v) { // 64-lane butterfly
    #pragma unroll
    for (int off = 32; off; off >>= 1) v += __shfl_xor(v, off, 64);
    return v;
}

// ---------- zero int region ----------
__global__ void k_zero(int* __restrict__ p, int n) {
    int i = blockIdx.x * blockDim.x + threadIdx.x;
    int i4 = i * 4;
    if (i4 + 3 < n) {
        reinterpret_cast<int4*>(p)[i] = make_int4(0, 0, 0, 0);
    } else {
        for (int k = i4; k < n; ++k) p[k] = 0;
    }
}

// ---------- setup: dtype detect + trel table + score constants ----------
// consts layout (floats): [0..6]=r.n  [8..14]=|r|^2  [16..22]=|n|^2
//                         [24..29]=tr.q  [32..37]=|tr|^2  [39]=|q|^2
__global__ void k_setup(const void* __restrict__ hour_emb, const void* __restrict__ W,
                        const void* __restrict__ bias, const void* __restrict__ rel_emb,
                        const void* __restrict__ norm_emb,
                        int* __restrict__ flag, float* __restrict__ trel,
                        float* __restrict__ consts) {
    int j = threadIdx.x;       // 0..63
    int hid = blockIdx.x;      // 0..5
    // local dtype detection (rel_emb rows L2-normalized -> |v|<=1 if truly bf16)
    float da = bf2f(reinterpret_cast<const unsigned short*>(rel_emb)[j]);
    float db = bf2f(reinterpret_cast<const unsigned short*>(rel_emb)[j + 64]);
    int bad = (!(fabsf(da) <= 100.f)) || (!(fabsf(db) <= 100.f));
    unsigned long long m = __ballot(bad);
    int f = (m != 0ull) ? 1 : 0;
    if (hid == 0 && j == 0) *flag = f;

    __shared__ float mix[D];
    int last = (hid - 1 + HOUR_PERIOD) % HOUR_PERIOD;
    int next = (hid + 1) % HOUR_PERIOD;
    mix[j] = (ld1(hour_emb, last * D + j, f) + ld1(hour_emb, hid * D + j, f) +
              ld1(hour_emb, next * D + j, f)) * (1.f / 3.f);
    __syncthreads();
    float y = ld1(bias, j, f);
    #pragma unroll
    for (int k = 0; k < D; ++k) y += mix[k] * ld1(W, j * D + k, f);
    float ss = wsum64(y * y);
    float tr = y / fmaxf(sqrtf(ss), 1e-12f);
    trel[hid * D + j] = tr;

    float q = ld1(norm_emb, 5 * D + j, f);   // time_norm
    float trq = wsum64(tr * q);
    float tt2 = wsum64(tr * tr);
    if (j == 0) { consts[24 + hid] = trq; consts[32 + hid] = tt2; }

    if (hid == 0) {
        float qq = wsum64(q * q);
        if (j == 0) consts[39] = qq;
        for (int ft = 0; ft < 7; ++ft) {
            float r = ld1(rel_emb, ft * D + j, f);
            float n = ld1(norm_emb, ft * D + j, f);
            float rn  = wsum64(r * n);
            float rr2 = wsum64(r * r);
            float nn  = wsum64(n * n);
            if (j == 0) { consts[ft] = rn; consts[8 + ft] = rr2; consts[16 + ft] = nn; }
        }
    }
}

// ---------- unified histogram over main (dst) + cat (N + cdst) ----------
__global__ void k_hist(const int* __restrict__ dst, const int* __restrict__ cdst,
                       int* __restrict__ cnt, int E, int EC, int N) {
    int i = blockIdx.x * blockDim.x + threadIdx.x;
    if (i >= E + EC) return;
    int d = (i < E) ? dst[i] : (N + cdst[i - E]);
    atomicAdd(&cnt[d], 1);
}

// ---------- hierarchical exclusive scan (chunk = 1024 per block) ----------
__global__ void k_scanA(const int* __restrict__ cnt, int* __restrict__ parts, int n) {
    __shared__ int sm[256];
    int t = threadIdx.x, b = blockIdx.x;
    int base = b * 1024 + t * 4;
    int s = 0;
    #pragma unroll
    for (int k = 0; k < 4; ++k) { int i = base + k; if (i < n) s += cnt[i]; }
    sm[t] = s; __syncthreads();
    #pragma unroll
    for (int off = 128; off; off >>= 1) {
        if (t < off) sm[t] += sm[t + off];
        __syncthreads();
    }
    if (t == 0) parts[b] = sm[0];
}
__global__ void k_scanB(int* __restrict__ parts, int nparts) {
    __shared__ int sm[256];
    int t = threadIdx.x;
    int v = (t < nparts) ? parts[t] : 0;
    sm[t] = v; __syncthreads();
    for (int off = 1; off < 256; off <<= 1) {
        int x = (t >= off) ? sm[t - off] : 0;
        __syncthreads();
        sm[t] += x;
        __syncthreads();
    }
    if (t < nparts) parts[t] = sm[t] - v;   // exclusive base per chunk
}
__global__ void k_scanC(const int* __restrict__ cnt, const int* __restrict__ parts,
                        int* __restrict__ row, int* __restrict__ cur, int n) {
    __shared__ int sm[256];
    int t = threadIdx.x, b = blockIdx.x;
    int base = b * 1024 + t * 4;
    int c[4]; int s = 0;
    #pragma unroll
    for (int k = 0; k < 4; ++k) { int i = base + k; c[k] = (i < n) ? cnt[i] : 0; s += c[k]; }
    sm[t] = s; __syncthreads();
    for (int off = 1; off < 256; off <<= 1) {
        int x = (t >= off) ? sm[t - off] : 0;
        __syncthreads();
        sm[t] += x;
        __syncthreads();
    }
    int inc = sm[t];
    int run = parts[b] + (inc - s);   // exclusive across threads
    #pragma unroll
    for (int k = 0; k < 4; ++k) {
        int i = base + k;
        if (i < n) {
            row[i] = run; cur[i] = run;
            if (i == n - 1) row[n] = run + c[k];
            run += c[k];
        }
    }
}

// ---------- unified scatter of packed edge records ----------
// main: src(17b) | ftype(3b)<<17 | hour(3b)<<20 ; cat: csrc plain
__global__ void k_scatter(const int* __restrict__ src, const int* __restrict__ dst,
                          const int* __restrict__ ft, const int* __restrict__ hh,
                          const int* __restrict__ csrc, const int* __restrict__ cdst,
                          int* __restrict__ cur, unsigned* __restrict__ recs,
                          int E, int EC, int N) {
    int i = blockIdx.x * blockDim.x + threadIdx.x;
    if (i >= E + EC) return;
    int d; unsigned pk;
    if (i < E) {
        d = dst[i];
        pk = (unsigned)src[i] | ((unsigned)ft[i] << 17) | ((unsigned)hh[i] << 20);
    } else {
        int j = i - E;
        d = N + cdst[j];
        pk = (unsigned)csrc[j];
    }
    int p = atomicAdd(&cur[d], 1);
    recs[p] = pk;
}

// ---------- fused aggregation for BOTH graphs ----------
// d < N: TransH*time score, rst[d] = sum es*h / sum es (softmax denom factors out)
// d >= N: TransE score over cat graph, output row d directly (concatenated layout)
__launch_bounds__(256)
__global__ void k_fused(const void* __restrict__ nfeat, const void* __restrict__ cemb,
                        const void* __restrict__ rel_emb, const void* __restrict__ norm_emb,
                        const float* __restrict__ trel, const float* __restrict__ consts,
                        const int* __restrict__ row, const unsigned* __restrict__ recs,
                        const int* __restrict__ flag, void* __restrict__ out,
                        int N, int M) {
    int f = *flag;
    __shared__ float srel[7 * D], snorm[7 * D], strel[HOUR_PERIOD * D], sc[40];
    int tid = threadIdx.x;
    for (int i = tid; i < 7 * D; i += 256) srel[i] = ld1(rel_emb, i, f);
    for (int i = tid; i < 7 * D; i += 256) snorm[i] = ld1(norm_emb, i, f);
    for (int i = tid; i < HOUR_PERIOD * D; i += 256) strel[i] = trel[i];
    if (tid < 40) sc[tid] = consts[tid];
    __syncthreads();
    int l = tid & 15;
    int d = blockIdx.x * 16 + (tid >> 4);
    if (d >= M) return;
    int i0 = row[d], i1 = row[d + 1];
    float a0 = 0.f, a1 = 0.f, a2 = 0.f, a3 = 0.f, se = 0.f;

    if (d < N) {
        // ---- main graph ----
        float4 tt = ld4(nfeat, d * 16 + l, f);
        float4 qv = *reinterpret_cast<float4*>(&snorm[5 * D + l * 4]);   // time_norm
        float qq2 = sc[39];
        unsigned pkA = 0, pkB = 0;
        float4 hA = make_float4(0,0,0,0), hB = hA;
        if (i0 < i1)     { pkA = recs[i0];     hA = ld4(nfeat, (int)(pkA & 0x1FFFF) * 16 + l, f); }
        if (i0 + 1 < i1) { pkB = recs[i0 + 1]; hB = ld4(nfeat, (int)(pkB & 0x1FFFF) * 16 + l, f); }
        for (int i = i0; i < i1; ++i) {
            unsigned cpk = pkA; float4 ch = hA;
            pkA = pkB; hA = hB;
            if (i + 2 < i1) { pkB = recs[i + 2]; hB = ld4(nfeat, (int)(pkB & 0x1FFFF) * 16 + l, f); }
            int ft = (cpk >> 17) & 7, hh = (cpk >> 20) & 7;
            float4 nn4 = *reinterpret_cast<float4*>(&snorm[ft * D + l * 4]);
            float4 rr4 = *reinterpret_cast<float4*>(&srel[ft * D + l * 4]);
            float4 tr4 = *reinterpret_cast<float4*>(&strel[hh * D + l * 4]);
            float w0 = ch.x - tt.x, w1 = ch.y - tt.y, w2 = ch.z - tt.z, w3 = ch.w - tt.w;
            // P = w.(w + r + tr);  alpha = w.n;  beta = w.q
            float s0 = w0 + rr4.x + tr4.x, s1 = w1 + rr4.y + tr4.y,
                  s2 = w2 + rr4.z + tr4.z, s3 = w3 + rr4.w + tr4.w;
            float P = qsum(w0*s0 + w1*s1 + w2*s2 + w3*s3);
            float al = qsum(w0*nn4.x + w1*nn4.y + w2*nn4.z + w3*nn4.w);
            float be = qsum(w0*qv.x + w1*qv.y + w2*qv.z + w3*qv.w);
            // ssq = |w+r-al*n|^2 + |w+tr-be*q|^2 expanded with precomputed constants
            float ssq = 2.f*P + sc[8 + ft] + sc[32 + hh]
                      - 2.f*al*(al + sc[ft])      + al*al*sc[16 + ft]
                      - 2.f*be*(be + sc[24 + hh]) + be*be*qq2;
            float es = __expf(__expf(-ssq));
            a0 += es * ch.x; a1 += es * ch.y; a2 += es * ch.z; a3 += es * ch.w;
            se += es;
        }
    } else {
        // ---- category graph (TransE) ----
        float4 tt = ld4(cemb, (d - N) * 16 + l, f);
        float4 r6 = *reinterpret_cast<float4*>(&srel[6 * D + l * 4]);
        float b0 = r6.x - tt.x, b1 = r6.y - tt.y, b2 = r6.z - tt.z, b3 = r6.w - tt.w;
        unsigned pkA = 0, pkB = 0;
        float4 hA = make_float4(0,0,0,0), hB = hA;
        if (i0 < i1)     { pkA = recs[i0];     hA = ld4(cemb, (int)pkA * 16 + l, f); }
        if (i0 + 1 < i1) { pkB = recs[i0 + 1]; hB = ld4(cemb, (int)pkB * 16 + l, f); }
        for (int i = i0; i < i1; ++i) {
            float4 ch = hA;
            pkA = pkB; hA = hB;
            if (i + 2 < i1) { pkB = recs[i + 2]; hB = ld4(cemb, (int)pkB * 16 + l, f); }
            float d0 = ch.x + b0, d1 = ch.y + b1, d2 = ch.z + b2, d3 = ch.w + b3;
            float ssq = qsum(d0*d0 + d1*d1 + d2*d2 + d3*d3);
            float es = __expf(__expf(-ssq));
            a0 += es * ch.x; a1 += es * ch.y; a2 += es * ch.z; a3 += es * ch.w;
            se += es;
        }
    }
    float inv = (se > 0.f) ? 1.f / se : 0.f;   // zero-degree row -> zeros
    int oi = d * 16 + l;
    if (f) {
        reinterpret_cast<float4*>(out)[oi] = make_float4(a0*inv, a1*inv, a2*inv, a3*inv);
    } else {
        ushort4 o;
        o.x = f2bf(a0*inv); o.y = f2bf(a1*inv); o.z = f2bf(a2*inv); o.w = f2bf(a3*inv);
        reinterpret_cast<ushort4*>(out)[oi] = o;
    }
}

extern "C" void kernel_launch(void* const* d_in, const int* in_sizes, int n_in,
                              void* d_out, int out_size, void* d_ws, size_t ws_size,
                              hipStream_t stream) {
    const void* nfeat    = d_in[0];
    const void* cemb     = d_in[1];
    const void* rel_emb  = d_in[2];
    const void* norm_emb = d_in[3];
    const void* hour_emb = d_in[4];
    const void* trw      = d_in[5];
    const void* trb      = d_in[6];
    const int* src    = (const int*)d_in[7];
    const int* dst    = (const int*)d_in[8];
    const int* ftype  = (const int*)d_in[9];
    const int* hourid = (const int*)d_in[10];
    const int* csrc   = (const int*)d_in[11];
    const int* cdst   = (const int*)d_in[12];

    const int N  = in_sizes[0] / D;
    const int NC = in_sizes[1] / D;
    const int E  = in_sizes[7];
    const int EC = in_sizes[11];
    const int M  = N + NC;          // unified dst space
    const int ET = E + EC;          // unified edge count

    // ---- ws layout (4B units) ----
    int* ws     = (int*)d_ws;
    int* flag   = ws;                               // 16
    float* trel = (float*)(ws + 16);                // HOUR_PERIOD*D
    float* consts = trel + HOUR_PERIOD * D;         // 40 + pad -> 64
    int* cnt    = ws + 16 + HOUR_PERIOD * D + 64;   // M
    int* row    = cnt + M;                          // M+1
    int* cur    = row + M + 1;                      // M
    int* parts  = cur + M;                          // 1024 (scan scratch)
    unsigned* recs = (unsigned*)(parts + 1024);     // ET

    k_zero<<<((M + 3) / 4 + 255) / 256, 256, 0, stream>>>(cnt, M);
    k_setup<<<HOUR_PERIOD, D, 0, stream>>>(hour_emb, trw, trb, rel_emb, norm_emb,
                                           flag, trel, consts);
    k_hist<<<(ET + 255) / 256, 256, 0, stream>>>(dst, cdst, cnt, E, EC, N);

    int nparts = (M + 1023) / 1024;
    k_scanA<<<nparts, 256, 0, stream>>>(cnt, parts, M);
    k_scanB<<<1, 256, 0, stream>>>(parts, nparts);
    k_scanC<<<nparts, 256, 0, stream>>>(cnt, parts, row, cur, M);

    k_scatter<<<(ET + 255) / 256, 256, 0, stream>>>(src, dst, ftype, hourid,
                                                    csrc, cdst, cur, recs, E, EC, N);
    k_fused<<<(M + 15) / 16, 256, 0, stream>>>(nfeat, cemb, rel_emb, norm_emb,
                                               trel, consts, row, recs, flag,
                                               d_out, N, M);
}